// Round 11
// baseline (70.664 us; speedup 1.0000x reference)
//
#include <hip/hip_runtime.h>

typedef float f32x4 __attribute__((ext_vector_type(4)));
typedef short bf16x8 __attribute__((ext_vector_type(8)));

#define HH 512
#define WW 512
#define NB 32
#define BT 64                 // strip width (px)
#define TH 32                 // tile height (output rows)
#define NT 8                  // tiles per block: 8 x 32 = 256 rows
#define TIH 36                // staged rows per tile (+-2 halo)
#define TIWP 68               // staged px per row (+-2 halo)
#define NPX (TIH * TIWP)      // 2448
#define NSLOT 10              // ceil(2448/256)
#define TAILT (NPX - 256 * (NSLOT - 1))   // 144
#define ROWB 560              // LDS row stride bytes (70 px * 8B)
#define EPS 1e-5f

__device__ __forceinline__ const __attribute__((address_space(4))) float*
cptr(const float* p) {
    return (const __attribute__((address_space(4))) float*)(unsigned long long)p;
}
__device__ __forceinline__ float ldw1(const float* p) { return cptr(p)[0]; }

__device__ __forceinline__ unsigned short f2bf(float f) {  // RNE float->bf16
    unsigned u = __float_as_uint(f);
    unsigned r = (u + 0x7FFFu + ((u >> 16) & 1u)) >> 16;
    return (unsigned short)r;
}

__device__ __forceinline__ float4 ldx4(const float* __restrict__ x, int b, int h, int w) {
    return *reinterpret_cast<const float4*>(x + ((((size_t)b * HH + h) * WW + w) << 2));
}

// ---- staging: global float4 -> regs (issue early), cvt+LDS write (late) ----
__device__ __forceinline__ void stage_load(const float* __restrict__ x, int b,
                                           int rin, int c0, bool chk,
                                           const int* tr, const int* tc,
                                           const int* goff, int t, float4 pf[NSLOT]) {
    if (!chk) {
        const float* pbase = x + (((size_t)b * HH + rin) * WW + (c0 - 2)) * 4;
#pragma unroll
        for (int j = 0; j < NSLOT; ++j) {
            if (j == NSLOT - 1 && t >= TAILT) continue;
            pf[j] = *reinterpret_cast<const float4*>(pbase + goff[j]);
        }
    } else {
#pragma unroll
        for (int j = 0; j < NSLOT; ++j) {
            if (j == NSLOT - 1 && t >= TAILT) continue;
            int gr = rin + tr[j];
            int gc = c0 - 2 + tc[j];
            float4 v = {0.f, 0.f, 0.f, 0.f};
            if (((unsigned)gr < (unsigned)HH) & ((unsigned)gc < (unsigned)WW))
                v = ldx4(x, b, gr, gc);
            pf[j] = v;
        }
    }
}

__device__ __forceinline__ void stage_write(char* __restrict__ buf,
                                            const int* tr, const int* tc, int t,
                                            const float4 pf[NSLOT]) {
#pragma unroll
    for (int j = 0; j < NSLOT; ++j) {
        if (j == NSLOT - 1 && t >= TAILT) continue;
        float4 p = pf[j];
        uint2 v;
        v.x = (unsigned)f2bf(p.x) | ((unsigned)f2bf(p.y) << 16);
        v.y = (unsigned)f2bf(p.z) | ((unsigned)f2bf(p.w) << 16);
        *reinterpret_cast<uint2*>(buf + tr[j] * ROWB + tc[j] * 8) = v;
    }
}

// ---- MFMA implicit-GEMM conv over NT pipelined tiles -----------------------
// mfma_f32_16x16x32_bf16: M=16 out rows, N=16=(4 shifts x 4 oc),
// K=32=(8 px x 4 ic).  B[k=(j,ic)][n=(s,oc)] = w[ki][j-s-OFF][ic][oc] or 0.
template <int K>
__device__ void conv_mfma_run(const float* __restrict__ x, float* __restrict__ out,
                              const float* __restrict__ wgt,
                              const float* __restrict__ gamma,
                              const float* __restrict__ beta,
                              const float* __restrict__ mean,
                              const float* __restrict__ var, int idx,
                              char* lds0, char* lds1,
                              int b, int r00, int c0, int t, bool wchk) {
    const int l  = t & 63, wv = t >> 6;
    const int n  = l & 15, kc = l >> 4;
    const int s  = n >> 2, oc = n & 3;
    constexpr int OFF = 2 - K / 2;

    // B fragments (once per block)
    bf16x8 Bf[K];
#pragma unroll
    for (int ki = 0; ki < K; ++ki) {
#pragma unroll
        for (int e = 0; e < 8; ++e) {
            int k = kc * 8 + e;
            int j = k >> 2, ic = k & 3;
            int jj = j - s - OFF;
            float v = (jj >= 0 && jj < K) ? wgt[((ki * K + jj) * 4 + ic) * 4 + oc] : 0.f;
            Bf[ki][e] = (short)f2bf(v);
        }
    }
    float iv = gamma[idx * 4 + oc] * rsqrtf(var[idx * 4 + oc] + EPS);
    float sh = beta[idx * 4 + oc] - mean[idx * 4 + oc] * iv;

    // staging coords (once per block)
    int tr[NSLOT], tc[NSLOT], goff[NSLOT];
#pragma unroll
    for (int j = 0; j < NSLOT; ++j) {
        int k = t + 256 * j;
        tr[j] = k / TIWP;
        tc[j] = k - tr[j] * TIWP;
        goff[j] = (tr[j] * WW + tc[j]) * 4;
    }

    // wave -> (row block, j0 half); lane row base inside buffer
    const int rb    = 16 * (wv & 1) + (l & 15) + OFF;
    const int j0beg = 8 * (wv >> 1);

    // prologue: stage tile 0
    float4 pf[NSLOT];
    stage_load(x, b, r00 - 2, c0, wchk | (r00 == 0), tr, tc, goff, t, pf);
    stage_write(lds0, tr, tc, t, pf);

#pragma unroll 1
    for (int i = 0; i < NT; ++i) {
        __syncthreads();
        char* bufC = (i & 1) ? lds1 : lds0;
        char* bufS = (i & 1) ? lds0 : lds1;
        if (i + 1 < NT) {
            int rin = r00 + (i + 1) * TH - 2;
            bool chk = wchk | (rin + TIH > HH);
            stage_load(x, b, rin, c0, chk, tr, tc, goff, t, pf);   // issue early
        }
        int r0i = r00 + i * TH;
        size_t obase = (((size_t)b * HH + r0i + 16 * (wv & 1) + kc * 4) * WW + c0 + s) * 4 + oc;
#pragma unroll
        for (int jj = 0; jj < 8; ++jj) {
            int j0 = j0beg + jj;
            f32x4 acc = {0.f, 0.f, 0.f, 0.f};
#pragma unroll
            for (int ki = 0; ki < K; ++ki) {
                bf16x8 a = *reinterpret_cast<const bf16x8*>(
                    bufC + (rb + ki) * ROWB + kc * 16 + j0 * 32);
                acc = __builtin_amdgcn_mfma_f32_16x16x32_bf16(a, Bf[ki], acc, 0, 0, 0);
            }
#pragma unroll
            for (int r = 0; r < 4; ++r) {
                float v = acc[r] * iv + sh;
                v = v > 0.f ? v : 0.f;
                out[obase + (size_t)r * (WW * 4) + j0 * 16] = v;
            }
        }
        if (i + 1 < NT) stage_write(bufS, tr, tc, t, pf);          // write late
    }
}

// ---- cold fallbacks (never selected with this input; correctness only) -----
struct BNs { float iv[4], sh[4]; };

__device__ __forceinline__ BNs make_bns(const float* gamma, const float* beta,
                                        const float* mean, const float* var, int idx) {
    BNs bn;
#pragma unroll
    for (int c = 0; c < 4; ++c) {
        float iv = ldw1(gamma + idx * 4 + c) * rsqrtf(ldw1(var + idx * 4 + c) + EPS);
        bn.iv[c] = iv;
        bn.sh[c] = ldw1(beta + idx * 4 + c) - ldw1(mean + idx * 4 + c) * iv;
    }
    return bn;
}

template <int K>
__device__ void conv_dw_naive(const float* __restrict__ x, float* __restrict__ out,
                              const float* __restrict__ wgt, const BNs& bn,
                              int b, int r00, int c0, int t) {
    int col = c0 + (t & 63);
    int rbs = r00 + (t >> 6) * 64;
    for (int rr = 0; rr < 64; ++rr) {
        int orow = rbs + rr;
        float a0 = 0.f, a1 = 0.f, a2 = 0.f, a3 = 0.f;
#pragma unroll
        for (int ki = 0; ki < K; ++ki) {
            int gr = orow + ki - K / 2;
            if ((unsigned)gr >= (unsigned)HH) continue;
#pragma unroll
            for (int kj = 0; kj < K; ++kj) {
                int gc = col + kj - K / 2;
                if ((unsigned)gc >= (unsigned)WW) continue;
                float4 p = ldx4(x, b, gr, gc);
                const float* wp = wgt + (ki * K + kj) * 4;
                a0 += p.x * wp[0]; a1 += p.y * wp[1];
                a2 += p.z * wp[2]; a3 += p.w * wp[3];
            }
        }
        float4 o;
        o.x = fmaxf(a0 * bn.iv[0] + bn.sh[0], 0.f);
        o.y = fmaxf(a1 * bn.iv[1] + bn.sh[1], 0.f);
        o.z = fmaxf(a2 * bn.iv[2] + bn.sh[2], 0.f);
        o.w = fmaxf(a3 * bn.iv[3] + bn.sh[3], 0.f);
        *reinterpret_cast<float4*>(out + ((((size_t)b * HH + orow) * WW + col) << 2)) = o;
    }
}

__device__ void conv_1x1(const float* __restrict__ x, float* __restrict__ out,
                         const float* __restrict__ w0, const BNs& bn,
                         int b, int r00, int c0, int t) {
    int col = c0 + (t & 63);
    int rbs = r00 + (t >> 6) * 64;
    for (int rr = 0; rr < 64; ++rr) {
        float4 p = ldx4(x, b, rbs + rr, col);
        float a0 = p.x * ldw1(w0 + 0) + p.y * ldw1(w0 + 4) + p.z * ldw1(w0 + 8)  + p.w * ldw1(w0 + 12);
        float a1 = p.x * ldw1(w0 + 1) + p.y * ldw1(w0 + 5) + p.z * ldw1(w0 + 9)  + p.w * ldw1(w0 + 13);
        float a2 = p.x * ldw1(w0 + 2) + p.y * ldw1(w0 + 6) + p.z * ldw1(w0 + 10) + p.w * ldw1(w0 + 14);
        float a3 = p.x * ldw1(w0 + 3) + p.y * ldw1(w0 + 7) + p.z * ldw1(w0 + 11) + p.w * ldw1(w0 + 15);
        float4 o;
        o.x = fmaxf(a0 * bn.iv[0] + bn.sh[0], 0.f);
        o.y = fmaxf(a1 * bn.iv[1] + bn.sh[1], 0.f);
        o.z = fmaxf(a2 * bn.iv[2] + bn.sh[2], 0.f);
        o.w = fmaxf(a3 * bn.iv[3] + bn.sh[3], 0.f);
        *reinterpret_cast<float4*>(out + ((((size_t)b * HH + rbs + rr) * WW + col) << 2)) = o;
    }
}

__global__ __launch_bounds__(256, 2) void mixop_kernel(
    const float* __restrict__ x,
    const float* __restrict__ logits, const float* __restrict__ g,
    const float* __restrict__ w0, const float* __restrict__ w1,
    const float* __restrict__ w2, const float* __restrict__ w3,
    const float* __restrict__ w4,
    const float* __restrict__ gamma, const float* __restrict__ beta,
    const float* __restrict__ mean, const float* __restrict__ var,
    float* __restrict__ out) {
    __shared__ __align__(16) char lds[2][TIH * ROWB];   // 2 x 19.7 KB

    int t    = threadIdx.x;
    int blk  = blockIdx.x;
    int bw   = blk & 7;            // 8 strips of 64 px
    int half = (blk >> 3) & 1;     // 2 row halves of 256
    int b    = blk >> 4;           // batch
    int c0   = bw * BT;
    int r00  = half * 256;
    bool wchk = (bw == 0) | (bw == 7);

    // wave-uniform routing: argmax(logits + g), first-max wins
    int idx = 0;
    float best = ldw1(logits + 0) + ldw1(g + 0);
#pragma unroll
    for (int i = 1; i < 5; ++i) {
        float v = ldw1(logits + i) + ldw1(g + i);
        if (v > best) { best = v; idx = i; }
    }

    switch (idx) {
        case 0: { BNs bn = make_bns(gamma, beta, mean, var, 0);
                  conv_1x1(x, out, w0, bn, b, r00, c0, t); break; }
        case 1: conv_mfma_run<3>(x, out, w1, gamma, beta, mean, var, 1,
                                 lds[0], lds[1], b, r00, c0, t, wchk); break;
        case 2: { BNs bn = make_bns(gamma, beta, mean, var, 2);
                  conv_dw_naive<3>(x, out, w2, bn, b, r00, c0, t); break; }
        case 3: conv_mfma_run<5>(x, out, w3, gamma, beta, mean, var, 3,
                                 lds[0], lds[1], b, r00, c0, t, wchk); break;
        case 4: { BNs bn = make_bns(gamma, beta, mean, var, 4);
                  conv_dw_naive<5>(x, out, w4, bn, b, r00, c0, t); break; }
    }
}

extern "C" void kernel_launch(void* const* d_in, const int* in_sizes, int n_in,
                              void* d_out, int out_size, void* d_ws, size_t ws_size,
                              hipStream_t stream) {
    const float* x      = (const float*)d_in[0];
    const float* logits = (const float*)d_in[1];
    const float* g      = (const float*)d_in[2];
    const float* w0     = (const float*)d_in[3];
    const float* w1     = (const float*)d_in[4];
    const float* w2     = (const float*)d_in[5];
    const float* w3     = (const float*)d_in[6];
    const float* w4     = (const float*)d_in[7];
    const float* gamma  = (const float*)d_in[8];
    const float* beta   = (const float*)d_in[9];
    const float* mean   = (const float*)d_in[10];
    const float* var    = (const float*)d_in[11];
    float* out = (float*)d_out;

    const int blocks = NB * 8 * 2;   // 512: 2 blocks/CU
    mixop_kernel<<<blocks, 256, 0, stream>>>(
        x, logits, g, w0, w1, w2, w3, w4, gamma, beta, mean, var, out);
}

// Round 12
// 54.626 us; speedup vs baseline: 1.2936x; 1.2936x over previous
//
#include <hip/hip_runtime.h>

typedef float f32x4 __attribute__((ext_vector_type(4)));
typedef short bf16x8 __attribute__((ext_vector_type(8)));

#define HH 512
#define WW 512
#define NB 32
#define BT 64                 // strip width (px)
#define TR 32                 // tile rows per block
#define TIH 36                // staged rows (+-2 halo)
#define TIWP 68               // staged px per row (+-2 halo)
#define NPX (TIH * TIWP)      // 2448
#define ROWB 560              // LDS row stride bytes (70 px * 8B)
#define EPS 1e-5f

// Wave-uniform loads via constant address space -> s_load.
__device__ __forceinline__ const __attribute__((address_space(4))) float*
cptr(const float* p) {
    return (const __attribute__((address_space(4))) float*)(unsigned long long)p;
}
__device__ __forceinline__ float ldw1(const float* p) { return cptr(p)[0]; }

__device__ __forceinline__ unsigned short f2bf(float f) {  // RNE float->bf16
    unsigned u = __float_as_uint(f);
    unsigned r = (u + 0x7FFFu + ((u >> 16) & 1u)) >> 16;
    return (unsigned short)r;
}

__device__ __forceinline__ float4 ldx4(const float* __restrict__ x, int b, int h, int w) {
    return *reinterpret_cast<const float4*>(x + ((((size_t)b * HH + h) * WW + w) << 2));
}

struct BNs { float iv[4], sh[4]; };

__device__ __forceinline__ BNs make_bns(const float* gamma, const float* beta,
                                        const float* mean, const float* var, int idx) {
    BNs bn;
#pragma unroll
    for (int c = 0; c < 4; ++c) {
        float iv = ldw1(gamma + idx * 4 + c) * rsqrtf(ldw1(var + idx * 4 + c) + EPS);
        bn.iv[c] = iv;
        bn.sh[c] = ldw1(beta + idx * 4 + c) - ldw1(mean + idx * 4 + c) * iv;
    }
    return bn;
}

// ---------------- MFMA path: full KxK conv (4->4 ch) via shifted-B implicit GEMM.
// One mfma_f32_16x16x32_bf16: M=16 output rows, N=16=(4 shifts x 4 oc),
// K=32=(8 px cols x 4 ic).  B[k=(j,ic)][n=(s,oc)] = w[ki][j-s-OFF][ic][oc] or 0.
// Accumulate over ki.  A rows stream from the bf16 LDS tile.  64x32 tile,
// R10 chassis: stage -> one barrier -> compute (cross-block TLP does overlap).
template <int K>
__device__ __forceinline__ void conv_mfma(const float* __restrict__ x,
                                          float* __restrict__ out,
                                          const float* __restrict__ wgt,
                                          const float* __restrict__ gamma,
                                          const float* __restrict__ beta,
                                          const float* __restrict__ mean,
                                          const float* __restrict__ var, int idx,
                                          char* lds, int b, int r0, int c0, int t) {
    const int l  = t & 63, wv = t >> 6;
    const int n  = l & 15, kc = l >> 4;      // n = MFMA col, kc = k-chunk
    const int s  = n >> 2, oc = n & 3;       // col -> (shift, out-channel)
    constexpr int OFF = 2 - K / 2;           // offset into the +-2 halo

    // B fragments, lane-resident (built once; divergent small reads)
    bf16x8 Bf[K];
#pragma unroll
    for (int ki = 0; ki < K; ++ki) {
#pragma unroll
        for (int e = 0; e < 8; ++e) {
            int k = kc * 8 + e;
            int j = k >> 2, ic = k & 3;
            int jj = j - s - OFF;
            float v = (jj >= 0 && jj < K) ? wgt[((ki * K + jj) * 4 + ic) * 4 + oc] : 0.f;
            Bf[ki][e] = (short)f2bf(v);
        }
    }

    // per-lane BN constants for this lane's fixed output channel
    float iv = gamma[idx * 4 + oc] * rsqrtf(var[idx * 4 + oc] + EPS);
    float sh = beta[idx * 4 + oc] - mean[idx * 4 + oc] * iv;

    // stage 36x68 px as packed bf16x4 (8B/px), zero-filled SAME halo
    for (int kk = t; kk < NPX; kk += 256) {
        int row = kk / TIWP;
        int tc  = kk - row * TIWP;
        int gr  = r0 - 2 + row;
        int gc  = c0 - 2 + tc;
        uint2 v = {0u, 0u};
        if (((unsigned)gr < (unsigned)HH) & ((unsigned)gc < (unsigned)WW)) {
            float4 p = ldx4(x, b, gr, gc);
            v.x = (unsigned)f2bf(p.x) | ((unsigned)f2bf(p.y) << 16);
            v.y = (unsigned)f2bf(p.z) | ((unsigned)f2bf(p.w) << 16);
        }
        *reinterpret_cast<uint2*>(lds + row * ROWB + tc * 8) = v;
    }
    __syncthreads();

    // wave -> (16-row block, j0 half)
    const int rbase = 16 * (wv & 1) + (l & 15) + OFF;
    const int j0beg = 8 * (wv >> 1);
    size_t obase = (((size_t)b * HH + r0 + 16 * (wv & 1) + kc * 4) * WW + c0 + s) * 4 + oc;

#pragma unroll 2
    for (int jj = 0; jj < 8; ++jj) {         // 4-col output groups across 64 px
        int j0 = j0beg + jj;
        f32x4 acc = {0.f, 0.f, 0.f, 0.f};
#pragma unroll
        for (int ki = 0; ki < K; ++ki) {
            bf16x8 a = *reinterpret_cast<const bf16x8*>(
                lds + (rbase + ki) * ROWB + kc * 16 + j0 * 32);
            acc = __builtin_amdgcn_mfma_f32_16x16x32_bf16(a, Bf[ki], acc, 0, 0, 0);
        }
#pragma unroll
        for (int r = 0; r < 4; ++r) {
            float v = acc[r] * iv + sh;
            v = v > 0.f ? v : 0.f;
            out[obase + (size_t)r * (WW * 4) + j0 * 16] = v;
        }
    }
}

// ---------------- cold fallbacks (never selected with this input; correctness only)
template <int K>
__device__ void conv_dw_naive(const float* __restrict__ x, float* __restrict__ out,
                              const float* __restrict__ wgt, const BNs& bn,
                              int b, int r0, int c0, int t) {
    int col = c0 + (t & 63);
    int rb  = r0 + (t >> 6) * 8;
    for (int rr = 0; rr < 8; ++rr) {
        int orow = rb + rr;
        float a0 = 0.f, a1 = 0.f, a2 = 0.f, a3 = 0.f;
#pragma unroll
        for (int ki = 0; ki < K; ++ki) {
            int gr = orow + ki - K / 2;
            if ((unsigned)gr >= (unsigned)HH) continue;
#pragma unroll
            for (int kj = 0; kj < K; ++kj) {
                int gc = col + kj - K / 2;
                if ((unsigned)gc >= (unsigned)WW) continue;
                float4 p = ldx4(x, b, gr, gc);
                const float* wp = wgt + (ki * K + kj) * 4;
                a0 += p.x * wp[0]; a1 += p.y * wp[1];
                a2 += p.z * wp[2]; a3 += p.w * wp[3];
            }
        }
        float4 o;
        o.x = fmaxf(a0 * bn.iv[0] + bn.sh[0], 0.f);
        o.y = fmaxf(a1 * bn.iv[1] + bn.sh[1], 0.f);
        o.z = fmaxf(a2 * bn.iv[2] + bn.sh[2], 0.f);
        o.w = fmaxf(a3 * bn.iv[3] + bn.sh[3], 0.f);
        *reinterpret_cast<float4*>(out + ((((size_t)b * HH + orow) * WW + col) << 2)) = o;
    }
}

__device__ void conv_1x1(const float* __restrict__ x, float* __restrict__ out,
                         const float* __restrict__ w0, const BNs& bn,
                         int b, int r0, int c0, int t) {
    int col = c0 + (t & 63);
    int rb  = r0 + (t >> 6) * 8;
    for (int rr = 0; rr < 8; ++rr) {
        float4 p = ldx4(x, b, rb + rr, col);
        float a0 = p.x * ldw1(w0 + 0) + p.y * ldw1(w0 + 4) + p.z * ldw1(w0 + 8)  + p.w * ldw1(w0 + 12);
        float a1 = p.x * ldw1(w0 + 1) + p.y * ldw1(w0 + 5) + p.z * ldw1(w0 + 9)  + p.w * ldw1(w0 + 13);
        float a2 = p.x * ldw1(w0 + 2) + p.y * ldw1(w0 + 6) + p.z * ldw1(w0 + 10) + p.w * ldw1(w0 + 14);
        float a3 = p.x * ldw1(w0 + 3) + p.y * ldw1(w0 + 7) + p.z * ldw1(w0 + 11) + p.w * ldw1(w0 + 15);
        float4 o;
        o.x = fmaxf(a0 * bn.iv[0] + bn.sh[0], 0.f);
        o.y = fmaxf(a1 * bn.iv[1] + bn.sh[1], 0.f);
        o.z = fmaxf(a2 * bn.iv[2] + bn.sh[2], 0.f);
        o.w = fmaxf(a3 * bn.iv[3] + bn.sh[3], 0.f);
        *reinterpret_cast<float4*>(out + ((((size_t)b * HH + rb + rr) * WW + col) << 2)) = o;
    }
}

__global__ __launch_bounds__(256, 8) void mixop_kernel(
    const float* __restrict__ x,
    const float* __restrict__ logits, const float* __restrict__ g,
    const float* __restrict__ w0, const float* __restrict__ w1,
    const float* __restrict__ w2, const float* __restrict__ w3,
    const float* __restrict__ w4,
    const float* __restrict__ gamma, const float* __restrict__ beta,
    const float* __restrict__ mean, const float* __restrict__ var,
    float* __restrict__ out) {
    __shared__ __align__(16) char lds[TIH * ROWB];   // 20.2 KB -> 8 blocks/CU

    int t   = threadIdx.x;
    int blk = blockIdx.x;
    int bw  = blk & 7;             // 8 col strips of 64 px
    int bh  = (blk >> 3) & 15;     // 16 row tiles of 32
    int b   = blk >> 7;            // batch
    int c0  = bw * BT;
    int r0  = bh * TR;

    // wave-uniform routing: argmax(logits + g), first-max wins
    int idx = 0;
    float best = ldw1(logits + 0) + ldw1(g + 0);
#pragma unroll
    for (int i = 1; i < 5; ++i) {
        float v = ldw1(logits + i) + ldw1(g + i);
        if (v > best) { best = v; idx = i; }
    }

    switch (idx) {
        case 0: { BNs bn = make_bns(gamma, beta, mean, var, 0);
                  conv_1x1(x, out, w0, bn, b, r0, c0, t); break; }
        case 1: conv_mfma<3>(x, out, w1, gamma, beta, mean, var, 1, lds, b, r0, c0, t); break;
        case 2: { BNs bn = make_bns(gamma, beta, mean, var, 2);
                  conv_dw_naive<3>(x, out, w2, bn, b, r0, c0, t); break; }
        case 3: conv_mfma<5>(x, out, w3, gamma, beta, mean, var, 3, lds, b, r0, c0, t); break;
        case 4: { BNs bn = make_bns(gamma, beta, mean, var, 4);
                  conv_dw_naive<5>(x, out, w4, bn, b, r0, c0, t); break; }
    }
}

extern "C" void kernel_launch(void* const* d_in, const int* in_sizes, int n_in,
                              void* d_out, int out_size, void* d_ws, size_t ws_size,
                              hipStream_t stream) {
    const float* x      = (const float*)d_in[0];
    const float* logits = (const float*)d_in[1];
    const float* g      = (const float*)d_in[2];
    const float* w0     = (const float*)d_in[3];
    const float* w1     = (const float*)d_in[4];
    const float* w2     = (const float*)d_in[5];
    const float* w3     = (const float*)d_in[6];
    const float* w4     = (const float*)d_in[7];
    const float* gamma  = (const float*)d_in[8];
    const float* beta   = (const float*)d_in[9];
    const float* mean   = (const float*)d_in[10];
    const float* var    = (const float*)d_in[11];
    float* out = (float*)d_out;

    const int blocks = NB * 8 * 16;   // 4096 tiles of 64x32
    mixop_kernel<<<blocks, 256, 0, stream>>>(
        x, logits, g, w0, w1, w2, w3, w4, gamma, beta, mean, var, out);
}